// Round 1
// baseline (361.652 us; speedup 1.0000x reference)
//
#include <hip/hip_runtime.h>

#define NPOS 16384
#define NEG  (-1e30f)

// workspace offsets (in floats)
#define OFF_WT_F 0
#define OFF_WH_F 4096
#define OFF_B_F  5120
#define OFF_WT_B 5184
#define OFF_WH_B 9280
#define OFF_B_B  10304
#define OFF_YP   10368
#define OFF_ZB   10608
#define OFF_FWDH 16384
#define OFF_BWDH (OFF_FWDH + 15*16384*16)
#define OFF_A    (OFF_BWDH + 15*16384*16)
#define OFF_T0   (OFF_A + 16384*16)
#define OFF_GSC  (OFF_T0 + 128*225)

__device__ __forceinline__ float sigf(float x) {
    return __builtin_amdgcn_rcpf(1.0f + __expf(-x));
}
__device__ __forceinline__ float tanhf_(float x) {
    return 1.0f - 2.0f * __builtin_amdgcn_rcpf(1.0f + __expf(2.0f * x));
}

// ---------------------------------------------------------------- prep
__global__ void k_prep(const float* __restrict__ fWih, const float* __restrict__ fWhh,
                       const float* __restrict__ fbih, const float* __restrict__ fbhh,
                       const float* __restrict__ bWih, const float* __restrict__ bWhh,
                       const float* __restrict__ bbih, const float* __restrict__ bbhh,
                       const float* __restrict__ Yenc, const float* __restrict__ Zenc,
                       const float* __restrict__ VW,   const float* __restrict__ Vb,
                       float* __restrict__ wp)
{
    int t = threadIdx.x;
    for (int e = t; e < 4096; e += 256) {           // WihT[k][j] = Wih[j][k]
        int j = e >> 6, k = e & 63;
        wp[OFF_WT_F + k*64 + j] = fWih[e];
        wp[OFF_WT_B + k*64 + j] = bWih[e];
    }
    for (int e = t; e < 1024; e += 256) {           // WhhT[m][j] = Whh[j][m]
        int j = e >> 4, m = e & 15;
        wp[OFF_WH_F + m*64 + j] = fWhh[e];
        wp[OFF_WH_B + m*64 + j] = bWhh[e];
    }
    for (int e = t; e < 64; e += 256) {
        wp[OFF_B_F + e] = fbih[e] + fbhh[e];
        wp[OFF_B_B + e] = bbih[e] + bbhh[e];
    }
    for (int e = t; e < 240; e += 256) {
        int y = e >> 4, h = e & 15;
        float acc = 0.f;                            // ypart = Y_enc @ V2^T
        for (int tt = 0; tt < 32; tt++) acc += Yenc[y*32+tt] * VW[h*68 + 32 + tt];
        wp[OFF_YP + e] = acc;
        float z = Vb[h];                            // zb = Z_enc @ V3^T + V_b
        for (int u = 0; u < 4; u++) z += Zenc[y*4+u] * VW[h*68 + 64 + u];
        wp[OFF_ZB + e] = z;
    }
}

// ---------------------------------------------------------------- LSTM (fwd+bwd)
// 256 blocks x 512 thr. wave 0-3: fwd gate-slices, wave 4-7: bwd. lane = position.
__global__ __launch_bounds__(512) void k_lstm(const float* __restrict__ data,
    const float* __restrict__ wp,
    const float* __restrict__ h0f, const float* __restrict__ c0f,
    const float* __restrict__ h0b, const float* __restrict__ c0b,
    float* __restrict__ ws)
{
    __shared__ float xs[92*65];       // data rows [P0-14, P0+78), stride 65 (conflict-free)
    __shared__ float gs[2*64*64];     // gates [dir][j][pos]
    __shared__ float hsh[2*16*64];    // h     [dir][m][pos]
    const int tid  = threadIdx.x;
    const int lane = tid & 63;
    const int wv   = __builtin_amdgcn_readfirstlane(tid >> 6);
    const int dir  = wv >> 2;
    const int js   = (wv & 3) << 4;   // gate slice start
    const int ms   = (wv & 3) << 2;   // hidden slice start (activation owner)
    const int P0   = blockIdx.x << 6;

    for (int idx = tid; idx < 92*64; idx += 512) {
        int r = idx >> 6, cc = idx & 63;
        int src = P0 - 14 + r;
        src = src < 0 ? 0 : (src > NPOS-1 ? NPOS-1 : src);
        xs[r*65 + cc] = data[src*64 + cc];
    }
    for (int idx = tid; idx < 2048; idx += 512) {
        int dd = idx >> 10, m = (idx >> 6) & 15;
        hsh[idx] = dd ? h0b[m] : h0f[m];
    }
    const float* WT  = wp + (dir ? OFF_WT_B : OFF_WT_F);
    const float* WHT = wp + (dir ? OFF_WH_B : OFF_WH_F);
    const float* bb  = wp + (dir ? OFF_B_B  : OFF_B_F);
    const float* c0  = dir ? c0b : c0f;
    float* outH = ws + (dir ? OFF_BWDH : OFF_FWDH);
    float c[4];
    #pragma unroll
    for (int mm = 0; mm < 4; mm++) c[mm] = c0[ms + mm];
    __syncthreads();

    for (int d = 0; d < 15; d++) {
        const int lr = dir ? (lane + 14 - d) : (lane + 14 + d);
        float part[16];
        #pragma unroll
        for (int jj = 0; jj < 16; jj++) part[jj] = bb[js + jj];
        #pragma unroll 4
        for (int k = 0; k < 64; k++) {
            float xk = xs[lr*65 + k];
            #pragma unroll
            for (int jj = 0; jj < 16; jj++)
                part[jj] = fmaf(WT[k*64 + js + jj], xk, part[jj]);
        }
        #pragma unroll
        for (int m = 0; m < 16; m++) {
            float hm = hsh[dir*1024 + m*64 + lane];
            #pragma unroll
            for (int jj = 0; jj < 16; jj++)
                part[jj] = fmaf(WHT[m*64 + js + jj], hm, part[jj]);
        }
        #pragma unroll
        for (int jj = 0; jj < 16; jj++)
            gs[dir*4096 + (js + jj)*64 + lane] = part[jj];
        __syncthreads();
        float hv[4];
        #pragma unroll
        for (int mm = 0; mm < 4; mm++) {
            int m = ms + mm;
            float gi = gs[dir*4096 + m*64 + lane];
            float gf = gs[dir*4096 + (16+m)*64 + lane];
            float gg = gs[dir*4096 + (32+m)*64 + lane];
            float go = gs[dir*4096 + (48+m)*64 + lane];
            float cn = sigf(gf)*c[mm] + sigf(gi)*tanhf_(gg);
            c[mm] = cn;
            hv[mm] = sigf(go)*tanhf_(cn);
            hsh[dir*1024 + m*64 + lane] = hv[mm];
        }
        float4 h4 = make_float4(hv[0], hv[1], hv[2], hv[3]);
        *(float4*)(outH + ((size_t)d*NPOS + P0 + lane)*16 + ms) = h4;
        __syncthreads();
    }
}

// ---------------------------------------------------------------- scores + A
// thread = (p, d); 960 blocks x 256 thr
__global__ __launch_bounds__(256) void k_scores(float* __restrict__ ws,
    const float* __restrict__ VW, const float* __restrict__ WW,
    const float* __restrict__ Wb)
{
    const int g = blockIdx.x * 256 + threadIdx.x;
    const int p = g & (NPOS - 1);
    const int d = __builtin_amdgcn_readfirstlane(g >> 14);
    float* A16 = ws + OFF_A;
    if (d == 0) A16[p*16 + 15] = NEG;   // pad column
    if (p < d) { A16[p*16 + d] = NEG; return; }

    const float* fptr = ws + OFF_FWDH + ((size_t)d*NPOS + (p - d))*16;
    const float* bptr = ws + OFF_BWDH + ((size_t)d*NPOS + p)*16;
    float fb0[16], fb1[16];
    #pragma unroll
    for (int q = 0; q < 4; q++) {
        float4 v = *(const float4*)(fptr + 4*q);
        fb0[4*q] = v.x; fb0[4*q+1] = v.y; fb0[4*q+2] = v.z; fb0[4*q+3] = v.w;
        float4 w4 = *(const float4*)(bptr + 4*q);
        fb1[4*q] = w4.x; fb1[4*q+1] = w4.y; fb1[4*q+2] = w4.z; fb1[4*q+3] = w4.w;
    }
    const float* zb = ws + OFF_ZB + d*16;
    const float* yp = ws + OFF_YP;
    float base[16];
    #pragma unroll
    for (int h = 0; h < 16; h++) {
        float acc = zb[h];
        #pragma unroll
        for (int m = 0; m < 16; m++) acc = fmaf(VW[h*68 + m],      fb0[m], acc);
        #pragma unroll
        for (int m = 0; m < 16; m++) acc = fmaf(VW[h*68 + 16 + m], fb1[m], acc);
        base[h] = acc;
    }
    const float wb = Wb[0];
    float sc[15];
    #pragma unroll
    for (int y = 0; y < 15; y++) {
        float a = wb;
        #pragma unroll
        for (int h = 0; h < 16; h++)
            a = fmaf(WW[h], tanhf_(base[h] + yp[y*16 + h]), a);
        sc[y] = a;
    }
    float mx = sc[0];
    #pragma unroll
    for (int y = 1; y < 15; y++) mx = fmaxf(mx, sc[y]);
    float ssum = 0.f;
    #pragma unroll
    for (int y = 0; y < 15; y++) ssum += __expf(sc[y] - mx);
    A16[p*16 + d] = mx + __logf(ssum);
    if (p == d && p < 15) {
        float* gsc = ws + OFF_GSC;
        #pragma unroll
        for (int y = 0; y < 15; y++) gsc[p*15 + y] = sc[y];
    }
}

// ---------------------------------------------------------------- DP chunk transfer matrices
// 128 chunks of 128 steps; thread = basis vector (15 active / block)
__global__ __launch_bounds__(64) void k_dp1(const float* __restrict__ ws, float* __restrict__ T0)
{
    __shared__ float la[2048];
    const int chunk = blockIdx.x;
    const int tid = threadIdx.x;
    const float* A16 = ws + OFF_A + (size_t)chunk * 2048;
    for (int idx = tid; idx < 2048; idx += 64) la[idx] = A16[idx];
    __syncthreads();
    if (tid >= 15) return;
    const int j = tid;
    float s[15];
    #pragma unroll
    for (int i = 0; i < 15; i++) s[i] = (i == j) ? 0.f : NEG;
    float a[15];
    #pragma unroll
    for (int i = 0; i < 15; i++) a[i] = la[i];
    for (int t = 0; t < 128; t++) {
        float nx[15];
        if (t < 127) {
            #pragma unroll
            for (int i = 0; i < 15; i++) nx[i] = la[(t+1)*16 + i];
        }
        float tv[15];
        float mx = s[0] + a[0];
        tv[0] = mx;
        #pragma unroll
        for (int i = 1; i < 15; i++) { tv[i] = s[i] + a[i]; mx = fmaxf(mx, tv[i]); }
        float ssum = 0.f;
        #pragma unroll
        for (int i = 0; i < 15; i++) ssum += __expf(tv[i] - mx);
        float nw = mx + __logf(ssum);
        #pragma unroll
        for (int i = 14; i > 0; i--) s[i] = s[i-1];
        s[0] = nw;
        if (t < 127) {
            #pragma unroll
            for (int i = 0; i < 15; i++) a[i] = nx[i];
        }
    }
    #pragma unroll
    for (int i = 0; i < 15; i++) T0[chunk*225 + i*15 + j] = s[i];
}

// ---------------------------------------------------------------- tree combine + indiv + out
__global__ __launch_bounds__(1024) void k_final(const float* __restrict__ ws,
    const int* __restrict__ tags, const int* __restrict__ lengths,
    float* __restrict__ out)
{
    __shared__ float TA[64*225];
    __shared__ float TB[32*225];
    __shared__ float red[16];
    const int tid = threadIdx.x;
    const float* T0 = ws + OFF_T0;
    // level 0: 128 -> 64 (global -> TA)
    for (int e = tid; e < 64*225; e += 1024) {
        int cpair = e / 225, r = e % 225;
        int i = r / 15, jj = r % 15;
        const float* lo = T0 + (2*cpair)*225;
        const float* hi = T0 + (2*cpair + 1)*225;
        float tv[15]; float mx = -3.4e38f;
        #pragma unroll
        for (int k = 0; k < 15; k++) { tv[k] = hi[i*15+k] + lo[k*15+jj]; mx = fmaxf(mx, tv[k]); }
        float ssum = 0.f;
        #pragma unroll
        for (int k = 0; k < 15; k++) ssum += __expf(tv[k] - mx);
        TA[e] = mx + __logf(ssum);
    }
    __syncthreads();
    int n = 64;
    float* cur = TA;
    float* oth = TB;
    while (n > 1) {
        int half = n >> 1;
        for (int e = tid; e < half*225; e += 1024) {
            int cpair = e / 225, r = e % 225;
            int i = r / 15, jj = r % 15;
            const float* lo = cur + (2*cpair)*225;
            const float* hi = cur + (2*cpair + 1)*225;
            float tv[15]; float mx = -3.4e38f;
            #pragma unroll
            for (int k = 0; k < 15; k++) { tv[k] = hi[i*15+k] + lo[k*15+jj]; mx = fmaxf(mx, tv[k]); }
            float ssum = 0.f;
            #pragma unroll
            for (int k = 0; k < 15; k++) ssum += __expf(tv[k] - mx);
            oth[e] = mx + __logf(ssum);
        }
        __syncthreads();
        float* tsw = cur; cur = oth; oth = tsw;
        n = half;
    }
    // indiv = sum over samples with length < 15 of scores[len-1, len-1, tag]
    const float* gsc = ws + OFF_GSC;
    float loc = 0.f;
    for (int s = tid; s < 2048; s += 1024) {
        int len = lengths[s];
        if (len < 15) loc += gsc[(len-1)*15 + tags[s]];
    }
    #pragma unroll
    for (int off = 32; off > 0; off >>= 1) loc += __shfl_down(loc, off);
    if ((tid & 63) == 0) red[tid >> 6] = loc;
    __syncthreads();
    if (tid == 0) {
        float ind = 0.f;
        #pragma unroll
        for (int w = 0; w < 16; w++) ind += red[w];
        out[0] = cur[0] - ind;
    }
}

// ---------------------------------------------------------------- launcher
extern "C" void kernel_launch(void* const* d_in, const int* in_sizes, int n_in,
                              void* d_out, int out_size, void* d_ws, size_t ws_size,
                              hipStream_t stream)
{
    const float* data = (const float*)d_in[0];
    const float* fWih = (const float*)d_in[1];
    const float* fWhh = (const float*)d_in[2];
    const float* fbih = (const float*)d_in[3];
    const float* fbhh = (const float*)d_in[4];
    const float* bWih = (const float*)d_in[5];
    const float* bWhh = (const float*)d_in[6];
    const float* bbih = (const float*)d_in[7];
    const float* bbhh = (const float*)d_in[8];
    const float* h0f  = (const float*)d_in[9];
    const float* c0f  = (const float*)d_in[10];
    const float* h0b  = (const float*)d_in[11];
    const float* c0b  = (const float*)d_in[12];
    const float* Yenc = (const float*)d_in[13];
    const float* Zenc = (const float*)d_in[14];
    const float* VW   = (const float*)d_in[15];
    const float* Vb   = (const float*)d_in[16];
    const float* WW   = (const float*)d_in[17];
    const float* Wb   = (const float*)d_in[18];
    const int* tags    = (const int*)d_in[19];
    const int* lengths = (const int*)d_in[20];
    float* ws  = (float*)d_ws;
    float* out = (float*)d_out;

    hipLaunchKernelGGL(k_prep, dim3(1), dim3(256), 0, stream,
                       fWih, fWhh, fbih, fbhh, bWih, bWhh, bbih, bbhh,
                       Yenc, Zenc, VW, Vb, ws);
    hipLaunchKernelGGL(k_lstm, dim3(256), dim3(512), 0, stream,
                       data, ws, h0f, c0f, h0b, c0b, ws);
    hipLaunchKernelGGL(k_scores, dim3(960), dim3(256), 0, stream,
                       ws, VW, WW, Wb);
    hipLaunchKernelGGL(k_dp1, dim3(128), dim3(64), 0, stream, ws, ws + OFF_T0);
    hipLaunchKernelGGL(k_final, dim3(1), dim3(1024), 0, stream,
                       ws, tags, lengths, out);
}

// Round 2
// 308.141 us; speedup vs baseline: 1.1737x; 1.1737x over previous
//
#include <hip/hip_runtime.h>

#define NPOS 16384
#define NEG  (-1e30f)

// workspace offsets (in floats)
#define OFF_WQ_F 0
#define OFF_WQ_B 5120
#define OFF_BQ_F 10240
#define OFF_BQ_B 10304
#define OFF_YP   10368
#define OFF_ZB   10608
// h states stored as bf16 (ushort); float-offset base, cast to ushort*
#define OFF_FWDH 16384
#define OFF_BWDH (OFF_FWDH + 15*16384*16/2)
#define OFF_A    (OFF_BWDH + 15*16384*16/2)
#define OFF_T0   (OFF_A + 16384*16)
#define OFF_GSC  (OFF_T0 + 128*225)

__device__ __forceinline__ float sigf(float x) {
    return __builtin_amdgcn_rcpf(1.0f + __expf(-x));
}
__device__ __forceinline__ float tanhf_(float x) {
    return 1.0f - 2.0f * __builtin_amdgcn_rcpf(1.0f + __expf(2.0f * x));
}
__device__ __forceinline__ float bf2f(unsigned short u) {
    unsigned int v = ((unsigned int)u) << 16;
    return __builtin_bit_cast(float, v);
}
__device__ __forceinline__ unsigned short f2bf(float f) {
    unsigned int b = __builtin_bit_cast(unsigned int, f);
    return (unsigned short)((b + 0x8000u) >> 16);
}

// ---------------------------------------------------------------- prep
// Packs weights so wave wv's 8 gates {g*16 + 2*wv + mm : g=0..3, mm=0..1}
// are contiguous: WQ[k*64 + wv*8 + (g*2+mm)], k in [0,80) (0-63: Wih col k,
// 64-79: Whh col k-64). Also bias fold + ypart/zb precompute.
__global__ void k_prep(const float* __restrict__ fWih, const float* __restrict__ fWhh,
                       const float* __restrict__ fbih, const float* __restrict__ fbhh,
                       const float* __restrict__ bWih, const float* __restrict__ bWhh,
                       const float* __restrict__ bbih, const float* __restrict__ bbhh,
                       const float* __restrict__ Yenc, const float* __restrict__ Zenc,
                       const float* __restrict__ VW,   const float* __restrict__ Vb,
                       float* __restrict__ wp)
{
    int t = threadIdx.x;
    for (int e = t; e < 10240; e += 256) {
        int dir = e / 5120, rem = e % 5120;
        int k = rem >> 6, widx = rem & 63;
        int w = widx >> 3, jj = widx & 7;
        int j = (jj >> 1) * 16 + 2 * w + (jj & 1);
        const float* Wih = dir ? bWih : fWih;
        const float* Whh = dir ? bWhh : fWhh;
        float v = (k < 64) ? Wih[j * 64 + k] : Whh[j * 16 + (k - 64)];
        wp[(dir ? OFF_WQ_B : OFF_WQ_F) + rem] = v;
    }
    for (int e = t; e < 128; e += 256) {
        int dir = e >> 6, widx = e & 63;
        int w = widx >> 3, jj = widx & 7;
        int j = (jj >> 1) * 16 + 2 * w + (jj & 1);
        const float* bi = dir ? bbih : fbih;
        const float* bh = dir ? bbhh : fbhh;
        wp[(dir ? OFF_BQ_B : OFF_BQ_F) + widx] = bi[j] + bh[j];
    }
    for (int e = t; e < 240; e += 256) {
        int y = e >> 4, h = e & 15;
        float acc = 0.f;                            // ypart = Y_enc @ V2^T
        for (int tt = 0; tt < 32; tt++) acc += Yenc[y*32+tt] * VW[h*68 + 32 + tt];
        wp[OFF_YP + e] = acc;
        float z = Vb[h];                            // zb = Z_enc @ V3^T + V_b
        for (int u = 0; u < 4; u++) z += Zenc[y*4+u] * VW[h*68 + 64 + u];
        wp[OFF_ZB + e] = z;
    }
}

// ---------------------------------------------------------------- LSTM
// grid (256, 2): blockIdx.y = dir. 512 thr = 8 waves; wave wv owns hidden
// units m = {2wv, 2wv+1} (all four gates i,f,g,o for them). lane = position.
// One barrier per step (hsh double-buffered). h written to global as bf16.
__global__ __launch_bounds__(512) void k_lstm(const float* __restrict__ data,
    const float* __restrict__ wp,
    const float* __restrict__ h0f, const float* __restrict__ c0f,
    const float* __restrict__ h0b, const float* __restrict__ c0b,
    float* __restrict__ ws)
{
    __shared__ float xs[78*65];       // x rows for this block+dir, stride 65
    __shared__ float hsh[2][16*64];   // double-buffered h
    const int tid  = threadIdx.x;
    const int lane = tid & 63;
    const int wv   = __builtin_amdgcn_readfirstlane(tid >> 6);
    const int dir  = blockIdx.y;
    const int ms   = wv << 1;         // hidden slice start
    const int P0   = blockIdx.x << 6;

    // stage x window: fwd rows src=P0+r (r=0..77); bwd src=P0+r-14
    for (int idx = tid; idx < 78*64; idx += 512) {
        int r = idx >> 6, cc = idx & 63;
        int src = P0 + r - (dir ? 14 : 0);
        src = src < 0 ? 0 : (src > NPOS-1 ? NPOS-1 : src);
        xs[r*65 + cc] = data[src*64 + cc];
    }
    {
        const float* h0 = dir ? h0b : h0f;
        for (int idx = tid; idx < 1024; idx += 512)
            hsh[0][idx] = h0[idx >> 6];
    }
    const float* WQ = wp + (dir ? OFF_WQ_B : OFF_WQ_F);
    const float* bQ = wp + (dir ? OFF_BQ_B : OFF_BQ_F);
    const float* c0 = dir ? c0b : c0f;
    unsigned int* outH = (unsigned int*)(ws + (dir ? OFF_BWDH : OFF_FWDH));
    float c0v = c0[ms], c1v = c0[ms + 1];
    __syncthreads();

    int buf = 0;
    for (int d = 0; d < 15; d++) {
        const int row = dir ? (lane + 14 - d) : (lane + d);
        float part[8];
        #pragma unroll
        for (int jj = 0; jj < 8; jj++) part[jj] = bQ[wv*8 + jj];
        const float* xrow = xs + row*65;
        #pragma unroll 8
        for (int k = 0; k < 64; k++) {
            float xk = xrow[k];
            #pragma unroll
            for (int jj = 0; jj < 8; jj++)
                part[jj] = fmaf(WQ[k*64 + wv*8 + jj], xk, part[jj]);
        }
        #pragma unroll
        for (int m = 0; m < 16; m++) {
            float hm = hsh[buf][m*64 + lane];
            #pragma unroll
            for (int jj = 0; jj < 8; jj++)
                part[jj] = fmaf(WQ[(64+m)*64 + wv*8 + jj], hm, part[jj]);
        }
        // gates: part[g*2+mm], g = {0:i,1:f,2:g,3:o}
        float cn0 = sigf(part[2])*c0v + sigf(part[0])*tanhf_(part[4]);
        float cn1 = sigf(part[3])*c1v + sigf(part[1])*tanhf_(part[5]);
        c0v = cn0; c1v = cn1;
        float h0v = sigf(part[6])*tanhf_(cn0);
        float h1v = sigf(part[7])*tanhf_(cn1);
        hsh[buf^1][ms*64 + lane]     = h0v;
        hsh[buf^1][(ms+1)*64 + lane] = h1v;
        unsigned int pk = (unsigned int)f2bf(h0v) | ((unsigned int)f2bf(h1v) << 16);
        outH[((size_t)d*NPOS + P0 + lane)*8 + wv] = pk;
        __syncthreads();
        buf ^= 1;
    }
}

// ---------------------------------------------------------------- scores + A
// thread = (p, d); 960 blocks x 256 thr; h read as bf16
__global__ __launch_bounds__(256) void k_scores(float* __restrict__ ws,
    const float* __restrict__ VW, const float* __restrict__ WW,
    const float* __restrict__ Wb)
{
    const int g = blockIdx.x * 256 + threadIdx.x;
    const int p = g & (NPOS - 1);
    const int d = __builtin_amdgcn_readfirstlane(g >> 14);
    float* A16 = ws + OFF_A;
    if (d == 0) A16[p*16 + 15] = NEG;   // pad column
    if (p < d) { A16[p*16 + d] = NEG; return; }

    const uint4* fptr = (const uint4*)((const unsigned short*)(ws + OFF_FWDH)
                        + ((size_t)d*NPOS + (p - d))*16);
    const uint4* bptr = (const uint4*)((const unsigned short*)(ws + OFF_BWDH)
                        + ((size_t)d*NPOS + p)*16);
    float fb0[16], fb1[16];
    #pragma unroll
    for (int q = 0; q < 2; q++) {
        uint4 v = fptr[q];
        unsigned int ww[4] = {v.x, v.y, v.z, v.w};
        #pragma unroll
        for (int t = 0; t < 4; t++) {
            fb0[q*8 + 2*t]     = bf2f((unsigned short)(ww[t] & 0xffff));
            fb0[q*8 + 2*t + 1] = bf2f((unsigned short)(ww[t] >> 16));
        }
        uint4 u = bptr[q];
        unsigned int uu[4] = {u.x, u.y, u.z, u.w};
        #pragma unroll
        for (int t = 0; t < 4; t++) {
            fb1[q*8 + 2*t]     = bf2f((unsigned short)(uu[t] & 0xffff));
            fb1[q*8 + 2*t + 1] = bf2f((unsigned short)(uu[t] >> 16));
        }
    }
    const float* zb = ws + OFF_ZB + d*16;
    const float* yp = ws + OFF_YP;
    float base[16];
    #pragma unroll
    for (int h = 0; h < 16; h++) {
        float acc = zb[h];
        #pragma unroll
        for (int m = 0; m < 16; m++) acc = fmaf(VW[h*68 + m],      fb0[m], acc);
        #pragma unroll
        for (int m = 0; m < 16; m++) acc = fmaf(VW[h*68 + 16 + m], fb1[m], acc);
        base[h] = acc;
    }
    const float wb = Wb[0];
    float sc[15];
    #pragma unroll
    for (int y = 0; y < 15; y++) {
        float a = wb;
        #pragma unroll
        for (int h = 0; h < 16; h++)
            a = fmaf(WW[h], tanhf_(base[h] + yp[y*16 + h]), a);
        sc[y] = a;
    }
    float mx = sc[0];
    #pragma unroll
    for (int y = 1; y < 15; y++) mx = fmaxf(mx, sc[y]);
    float ssum = 0.f;
    #pragma unroll
    for (int y = 0; y < 15; y++) ssum += __expf(sc[y] - mx);
    A16[p*16 + d] = mx + __logf(ssum);
    if (p == d && p < 15) {
        float* gsc = ws + OFF_GSC;
        #pragma unroll
        for (int y = 0; y < 15; y++) gsc[p*15 + y] = sc[y];
    }
}

// ---------------------------------------------------------------- DP chunk transfer matrices
// 128 chunks of 128 steps; thread = basis vector (15 active / block)
__global__ __launch_bounds__(64) void k_dp1(const float* __restrict__ ws, float* __restrict__ T0)
{
    __shared__ float la[2048];
    const int chunk = blockIdx.x;
    const int tid = threadIdx.x;
    const float* A16 = ws + OFF_A + (size_t)chunk * 2048;
    for (int idx = tid; idx < 2048; idx += 64) la[idx] = A16[idx];
    __syncthreads();
    if (tid >= 15) return;
    const int j = tid;
    float s[15];
    #pragma unroll
    for (int i = 0; i < 15; i++) s[i] = (i == j) ? 0.f : NEG;
    float a[15];
    #pragma unroll
    for (int i = 0; i < 15; i++) a[i] = la[i];
    for (int t = 0; t < 128; t++) {
        float nx[15];
        if (t < 127) {
            #pragma unroll
            for (int i = 0; i < 15; i++) nx[i] = la[(t+1)*16 + i];
        }
        float tv[15];
        float mx = s[0] + a[0];
        tv[0] = mx;
        #pragma unroll
        for (int i = 1; i < 15; i++) { tv[i] = s[i] + a[i]; mx = fmaxf(mx, tv[i]); }
        float ssum = 0.f;
        #pragma unroll
        for (int i = 0; i < 15; i++) ssum += __expf(tv[i] - mx);
        float nw = mx + __logf(ssum);
        #pragma unroll
        for (int i = 14; i > 0; i--) s[i] = s[i-1];
        s[0] = nw;
        if (t < 127) {
            #pragma unroll
            for (int i = 0; i < 15; i++) a[i] = nx[i];
        }
    }
    #pragma unroll
    for (int i = 0; i < 15; i++) T0[chunk*225 + i*15 + j] = s[i];
}

// ---------------------------------------------------------------- tree combine + indiv + out
__global__ __launch_bounds__(1024) void k_final(const float* __restrict__ ws,
    const int* __restrict__ tags, const int* __restrict__ lengths,
    float* __restrict__ out)
{
    __shared__ float TA[64*225];
    __shared__ float TB[32*225];
    __shared__ float red[16];
    const int tid = threadIdx.x;
    const float* T0 = ws + OFF_T0;
    for (int e = tid; e < 64*225; e += 1024) {
        int cpair = e / 225, r = e % 225;
        int i = r / 15, jj = r % 15;
        const float* lo = T0 + (2*cpair)*225;
        const float* hi = T0 + (2*cpair + 1)*225;
        float tv[15]; float mx = -3.4e38f;
        #pragma unroll
        for (int k = 0; k < 15; k++) { tv[k] = hi[i*15+k] + lo[k*15+jj]; mx = fmaxf(mx, tv[k]); }
        float ssum = 0.f;
        #pragma unroll
        for (int k = 0; k < 15; k++) ssum += __expf(tv[k] - mx);
        TA[e] = mx + __logf(ssum);
    }
    __syncthreads();
    int n = 64;
    float* cur = TA;
    float* oth = TB;
    while (n > 1) {
        int half = n >> 1;
        for (int e = tid; e < half*225; e += 1024) {
            int cpair = e / 225, r = e % 225;
            int i = r / 15, jj = r % 15;
            const float* lo = cur + (2*cpair)*225;
            const float* hi = cur + (2*cpair + 1)*225;
            float tv[15]; float mx = -3.4e38f;
            #pragma unroll
            for (int k = 0; k < 15; k++) { tv[k] = hi[i*15+k] + lo[k*15+jj]; mx = fmaxf(mx, tv[k]); }
            float ssum = 0.f;
            #pragma unroll
            for (int k = 0; k < 15; k++) ssum += __expf(tv[k] - mx);
            oth[e] = mx + __logf(ssum);
        }
        __syncthreads();
        float* tsw = cur; cur = oth; oth = tsw;
        n = half;
    }
    const float* gsc = ws + OFF_GSC;
    float loc = 0.f;
    for (int s = tid; s < 2048; s += 1024) {
        int len = lengths[s];
        if (len < 15) loc += gsc[(len-1)*15 + tags[s]];
    }
    #pragma unroll
    for (int off = 32; off > 0; off >>= 1) loc += __shfl_down(loc, off);
    if ((tid & 63) == 0) red[tid >> 6] = loc;
    __syncthreads();
    if (tid == 0) {
        float ind = 0.f;
        #pragma unroll
        for (int w = 0; w < 16; w++) ind += red[w];
        out[0] = cur[0] - ind;
    }
}

// ---------------------------------------------------------------- launcher
extern "C" void kernel_launch(void* const* d_in, const int* in_sizes, int n_in,
                              void* d_out, int out_size, void* d_ws, size_t ws_size,
                              hipStream_t stream)
{
    const float* data = (const float*)d_in[0];
    const float* fWih = (const float*)d_in[1];
    const float* fWhh = (const float*)d_in[2];
    const float* fbih = (const float*)d_in[3];
    const float* fbhh = (const float*)d_in[4];
    const float* bWih = (const float*)d_in[5];
    const float* bWhh = (const float*)d_in[6];
    const float* bbih = (const float*)d_in[7];
    const float* bbhh = (const float*)d_in[8];
    const float* h0f  = (const float*)d_in[9];
    const float* c0f  = (const float*)d_in[10];
    const float* h0b  = (const float*)d_in[11];
    const float* c0b  = (const float*)d_in[12];
    const float* Yenc = (const float*)d_in[13];
    const float* Zenc = (const float*)d_in[14];
    const float* VW   = (const float*)d_in[15];
    const float* Vb   = (const float*)d_in[16];
    const float* WW   = (const float*)d_in[17];
    const float* Wb   = (const float*)d_in[18];
    const int* tags    = (const int*)d_in[19];
    const int* lengths = (const int*)d_in[20];
    float* ws  = (float*)d_ws;
    float* out = (float*)d_out;

    hipLaunchKernelGGL(k_prep, dim3(1), dim3(256), 0, stream,
                       fWih, fWhh, fbih, fbhh, bWih, bWhh, bbih, bbhh,
                       Yenc, Zenc, VW, Vb, ws);
    hipLaunchKernelGGL(k_lstm, dim3(256, 2), dim3(512), 0, stream,
                       data, ws, h0f, c0f, h0b, c0b, ws);
    hipLaunchKernelGGL(k_scores, dim3(960), dim3(256), 0, stream,
                       ws, VW, WW, Wb);
    hipLaunchKernelGGL(k_dp1, dim3(128), dim3(64), 0, stream, ws, ws + OFF_T0);
    hipLaunchKernelGGL(k_final, dim3(1), dim3(1024), 0, stream,
                       ws, tags, lengths, out);
}